// Round 8
// baseline (372.926 us; speedup 1.0000x reference)
//
#include <hip/hip_runtime.h>
#include <hip/hip_fp16.h>
#include <math.h>

#define NPTS 262144
#define PLANE_ELEMS 16777216u   // 256*256*256

typedef __attribute__((ext_vector_type(4))) float f4;
typedef __attribute__((ext_vector_type(4))) unsigned int u4;

// ws layout (bytes):
//   [0, 96 MB)        : fp16 planes, layout [plane][c_hi=16][hw=65536][c_lo=16]
//   +12.58 MB         : sortedC float4[3][NPTS] (c0,c1,c2,bits(n))
//   +25.17 MB         : partial fp16[3][NPTS][16]
//   +0.75 MB          : hist unsigned[3][65536]
#define OFF_SORTED   (3ull * PLANE_ELEMS * 2ull)
#define OFF_PARTIAL  (OFF_SORTED + (size_t)3 * NPTS * 16)
#define OFF_HIST     (OFF_PARTIAL + (size_t)3 * NPTS * 16 * 2)
#define WS_NEED      (OFF_HIST + (size_t)3 * 65536 * 4)

__device__ __forceinline__ void plane_xy(int p, float c0, float c1, float c2,
                                         float& gx, float& gy, float& ax) {
  if (p == 0)      { gx = c1; gy = c2; ax = c0; }
  else if (p == 1) { gx = c0; gy = c2; ax = c1; }
  else             { gx = c0; gy = c1; ax = c2; }
}

__device__ __forceinline__ int cell_of(float g) {
  float i = (g + 1.f) * 0.5f * 255.f;
  int x0 = (int)floorf(i);
  return x0 < 0 ? 0 : (x0 > 255 ? 255 : x0);
}

// ---------------------------------------------------------------------------
// Transpose + convert, register-only (no LDS):
// (C=256, hw) fp32 -> [c_hi=16][hw][c_lo=16] fp16.
// grid (64, 16, 3), block 256. Thread owns 4 hw x 16 c:
//   reads 16 float4 (wave: 1KB contiguous per row), transposes in registers,
//   stores 8 x 16B (wave k-step: 32B/lane @128B stride; 4 k-steps fill the
//   8KB span -> full sectors from the same wave, L2 merges).
// ---------------------------------------------------------------------------
__global__ __launch_bounds__(256) void PREFFFT_trans_k(
    const float* __restrict__ Pu, const float* __restrict__ Pv,
    const float* __restrict__ Pw, __half* __restrict__ dst0) {
  const float* src = blockIdx.z == 0 ? Pu : (blockIdx.z == 1 ? Pv : Pw);
  __half* dst = dst0 + (size_t)blockIdx.z * PLANE_ELEMS;
  const unsigned c_hi = blockIdx.y;                          // 0..15
  const unsigned hw = blockIdx.x * 1024u + threadIdx.x * 4u; // first of 4 hw

  const float* base = src + (size_t)(c_hi * 16u) * 65536u + hw;
  f4 v[16];
#pragma unroll
  for (int i = 0; i < 16; ++i)
    v[i] = *(const f4*)(base + (size_t)i * 65536u);

  __half* d = dst + (size_t)c_hi * 1048576u + (size_t)hw * 16u;
#pragma unroll
  for (int k = 0; k < 4; ++k) {
    unsigned w[8];
#pragma unroll
    for (int j = 0; j < 8; ++j) {
      __half2 h = __floats2half2_rn(v[2 * j][k], v[2 * j + 1][k]);
      w[j] = *(unsigned*)&h;
    }
    u4 lo{w[0], w[1], w[2], w[3]};
    u4 hi{w[4], w[5], w[6], w[7]};
    *(u4*)(d + k * 16) = lo;
    *(u4*)(d + k * 16 + 8) = hi;
  }
}

// ---------------------------------------------------------------------------
// Counting sort: histogram / scan / scatter (16-bit plane-cell keys).
// ---------------------------------------------------------------------------
__global__ __launch_bounds__(256) void PREFFFT_hist_k(
    const float* __restrict__ inputs, unsigned* __restrict__ hist) {
  int n = blockIdx.x * 256 + threadIdx.x;
  if (n >= NPTS) return;
  float c0 = inputs[n * 3 + 0], c1 = inputs[n * 3 + 1], c2 = inputs[n * 3 + 2];
#pragma unroll
  for (int p = 0; p < 3; ++p) {
    float gx, gy, ax;
    plane_xy(p, c0, c1, c2, gx, gy, ax);
    int key = (cell_of(gy) << 8) | cell_of(gx);
    atomicAdd(&hist[p * 65536 + key], 1u);
  }
}

__global__ __launch_bounds__(1024) void PREFFFT_scan_k(unsigned* __restrict__ hist) {
  __shared__ unsigned part[1024];
  unsigned* h = hist + (size_t)blockIdx.x * 65536;
  int t = threadIdx.x;
  unsigned s = 0;
#pragma unroll 8
  for (int i = 0; i < 64; ++i) s += h[t * 64 + i];
  part[t] = s;
  __syncthreads();
  for (int off = 1; off < 1024; off <<= 1) {
    unsigned v = (t >= off) ? part[t - off] : 0u;
    __syncthreads();
    part[t] += v;
    __syncthreads();
  }
  unsigned run = (t == 0) ? 0u : part[t - 1];
#pragma unroll 8
  for (int i = 0; i < 64; ++i) {
    unsigned c = h[t * 64 + i];
    h[t * 64 + i] = run;
    run += c;
  }
}

__global__ __launch_bounds__(256) void PREFFFT_scat_k(
    const float* __restrict__ inputs, unsigned* __restrict__ hist,
    float4* __restrict__ sortedC) {
  int n = blockIdx.x * 256 + threadIdx.x;
  if (n >= NPTS) return;
  float c0 = inputs[n * 3 + 0], c1 = inputs[n * 3 + 1], c2 = inputs[n * 3 + 2];
#pragma unroll
  for (int p = 0; p < 3; ++p) {
    float gx, gy, ax;
    plane_xy(p, c0, c1, c2, gx, gy, ax);
    int key = (cell_of(gy) << 8) | cell_of(gx);
    unsigned pos = atomicAdd(&hist[p * 65536 + key], 1u);
    sortedC[(size_t)p * NPTS + pos] =
        make_float4(c0, c1, c2, __uint_as_float((unsigned)n));
  }
}

// ---------------------------------------------------------------------------
// Sample pass: 8 lanes/point. Lane t owns re-ch2 {2t,2t+1} (plane ch t*16..+15
// = region c_hi=t) and im (region c_hi=8+t). Bilinear in packed fp16;
// Fourier dots in f32 with shared double-angle trig. fp16 partials by n.
// grid (NPTS/32, 3), block 256.
// ---------------------------------------------------------------------------
__global__ __launch_bounds__(256) void PREFFFT_samp_k(
    const float4* __restrict__ sortedC, const __half* __restrict__ T,
    __half* __restrict__ partial) {
  int p = blockIdx.y;
  int bx = blockIdx.x;                      // 0..8191
  int lbx = (bx & 7) * 1024 + (bx >> 3);    // XCD-contiguous chunks
  int slot = lbx * 32 + ((int)threadIdx.x >> 3);
  int t = threadIdx.x & 7;

  float4 sc = sortedC[(size_t)p * NPTS + slot];
  unsigned n = __float_as_uint(sc.w);
  float gx, gy, ax;
  plane_xy(p, sc.x, sc.y, sc.z, gx, gy, ax);

  float ix = (gx + 1.f) * 0.5f * 255.f;
  float iy = (gy + 1.f) * 0.5f * 255.f;
  float x0f = floorf(ix), y0f = floorf(iy);
  float wx = ix - x0f, wy = iy - y0f;
  int x0 = (int)x0f; x0 = x0 < 0 ? 0 : (x0 > 255 ? 255 : x0);
  int y0 = (int)y0f; y0 = y0 < 0 ? 0 : (y0 > 255 ? 255 : y0);
  int x1 = x0 + 1 > 255 ? 255 : x0 + 1;
  int y1 = y0 + 1 > 255 ? 255 : y0 + 1;
  float w00 = (1.f - wx) * (1.f - wy);
  float w01 = wx * (1.f - wy);
  float w10 = (1.f - wx) * wy;
  float w11 = wx * wy;

  const __half* __restrict__ Pre =
      T + (size_t)p * PLANE_ELEMS + (size_t)t * 1048576u;
  const __half* __restrict__ Pim = Pre + 8u * 1048576u;
  int r00 = (y0 * 256 + x0) * 16, r01 = (y0 * 256 + x1) * 16;
  int r10 = (y1 * 256 + x0) * 16, r11 = (y1 * 256 + x1) * 16;

  // 16 x 16B loads (4 corners x {re_lo, re_hi, im_lo, im_hi})
  f4 a0 = *(const f4*)(Pre + r00),   a1 = *(const f4*)(Pre + r00 + 8);
  f4 a2 = *(const f4*)(Pim + r00),   a3 = *(const f4*)(Pim + r00 + 8);
  f4 b0 = *(const f4*)(Pre + r01),   b1 = *(const f4*)(Pre + r01 + 8);
  f4 b2 = *(const f4*)(Pim + r01),   b3 = *(const f4*)(Pim + r01 + 8);
  f4 c0v = *(const f4*)(Pre + r10),  c1v = *(const f4*)(Pre + r10 + 8);
  f4 c2v = *(const f4*)(Pim + r10),  c3v = *(const f4*)(Pim + r10 + 8);
  f4 d0 = *(const f4*)(Pre + r11),   d1 = *(const f4*)(Pre + r11 + 8);
  f4 d2 = *(const f4*)(Pim + r11),   d3 = *(const f4*)(Pim + r11 + 8);

  __half2 hw00 = __float2half2_rn(w00), hw01 = __float2half2_rn(w01);
  __half2 hw10 = __float2half2_rn(w10), hw11 = __float2half2_rn(w11);

  // bilinear blend in packed fp16: 16 h2 outputs (8 re, 8 im)
  __half2 bre[8], bim[8];
#pragma unroll
  for (int q = 0; q < 4; ++q) {
    __half2 v;
    v = __hmul2(((const __half2*)&a0)[q], hw00);
    v = __hfma2(((const __half2*)&b0)[q],  hw01, v);
    v = __hfma2(((const __half2*)&c0v)[q], hw10, v);
    bre[q] = __hfma2(((const __half2*)&d0)[q], hw11, v);

    v = __hmul2(((const __half2*)&a1)[q], hw00);
    v = __hfma2(((const __half2*)&b1)[q],  hw01, v);
    v = __hfma2(((const __half2*)&c1v)[q], hw10, v);
    bre[q + 4] = __hfma2(((const __half2*)&d1)[q], hw11, v);

    v = __hmul2(((const __half2*)&a2)[q], hw00);
    v = __hfma2(((const __half2*)&b2)[q],  hw01, v);
    v = __hfma2(((const __half2*)&c2v)[q], hw10, v);
    bim[q] = __hfma2(((const __half2*)&d2)[q], hw11, v);

    v = __hmul2(((const __half2*)&a3)[q], hw00);
    v = __hfma2(((const __half2*)&b3)[q],  hw01, v);
    v = __hfma2(((const __half2*)&c3v)[q], hw10, v);
    bim[q + 4] = __hfma2(((const __half2*)&d3)[q], hw11, v);
  }

  // unpack to f32: fre[0..7] = ch2=2t r=0..7; fre[8..15] = ch2=2t+1
  float fre[16], fim[16];
#pragma unroll
  for (int q = 0; q < 8; ++q) {
    float2 vr = __half22float2(bre[q]);
    float2 vi = __half22float2(bim[q]);
    fre[2 * q] = vr.x; fre[2 * q + 1] = vr.y;
    fim[2 * q] = vi.x; fim[2 * q + 1] = vi.y;
  }

  // Fourier: theta_r = theta1 * 2^(r-1); r=0 term cos=1 / sin=0.
  float cs = (ax + 1.f) * 0.5f * 255.f;
  float th = 6.283185307179586f * cs * (1.f / 256.f);
  float s, c;
  __sincosf(th, &s, &c);
  float aR0 = fre[0], aR1 = fre[8];
  float aI0 = 0.f,    aI1 = 0.f;
#pragma unroll
  for (int r = 1; r < 8; ++r) {
    aR0 += fre[r] * c;     aR1 += fre[8 + r] * c;
    aI0 += fim[r] * s;     aI1 += fim[8 + r] * s;
    if (r < 7) {
      float c2 = c + c;
      float cn = c2 * c - 1.f;   // cos(2a) = 2cos^2 - 1
      s = c2 * s;                // sin(2a) = 2 sin cos
      c = cn;
    }
  }

  *(__half2*)(partial + ((size_t)p * NPTS + n) * 16 + 2 * t) =
      __floats2half2_rn(aR0 - aI0, aR1 - aI1);
}

// ---------------------------------------------------------------------------
// Reduce: out = sum of 3 fp16 partials, f32 output. 8 outputs/thread.
// ---------------------------------------------------------------------------
__global__ __launch_bounds__(256) void PREFFFT_red_k(
    const __half* __restrict__ part, float* __restrict__ out) {
  size_t i = (size_t)blockIdx.x * 256 + threadIdx.x;  // < 524288
  const size_t PS = (size_t)NPTS * 16;
  union H8 { u4 v; __half2 h[4]; };
  H8 a, b, c;
  a.v = *(const u4*)(part + i * 8);
  b.v = *(const u4*)(part + PS + i * 8);
  c.v = *(const u4*)(part + 2 * PS + i * 8);
  f4 o0, o1;
#pragma unroll
  for (int k = 0; k < 4; ++k) {
    float2 fa = __half22float2(a.h[k]);
    float2 fb = __half22float2(b.h[k]);
    float2 fc = __half22float2(c.h[k]);
    float lo = fa.x + fb.x + fc.x;
    float hi = fa.y + fb.y + fc.y;
    if (k < 2) { o0[2 * k] = lo; o0[2 * k + 1] = hi; }
    else       { o1[2 * (k - 2)] = lo; o1[2 * (k - 2) + 1] = hi; }
  }
  ((f4*)out)[i * 2] = o0;
  ((f4*)out)[i * 2 + 1] = o1;
}

// ---------------------------------------------------------------------------
// Fallback (ws too small): original (C,H,W) fp32 direct, slow but correct.
// ---------------------------------------------------------------------------
__global__ __launch_bounds__(256) void PREFFFT_fallback_k(
    const float* __restrict__ inputs, const float* __restrict__ Tu,
    const float* __restrict__ Tv, const float* __restrict__ Tw,
    float* __restrict__ out) {
  int gtid = blockIdx.x * 256 + threadIdx.x;
  int n = gtid >> 5;
  int t = threadIdx.x & 31;
  const bool is_re = t < 16;
  float c0 = inputs[n * 3 + 0], c1 = inputs[n * 3 + 1], c2 = inputs[n * 3 + 2];
  const float* PL[3] = {Tu, Tv, Tw};
  float acc = 0.f;
#pragma unroll
  for (int p = 0; p < 3; ++p) {
    float gx, gy, ax;
    plane_xy(p, c0, c1, c2, gx, gy, ax);
    float ix = (gx + 1.f) * 0.5f * 255.f;
    float iy = (gy + 1.f) * 0.5f * 255.f;
    float x0f = floorf(ix), y0f = floorf(iy);
    float wx = ix - x0f, wy = iy - y0f;
    int x0 = (int)x0f; x0 = x0 < 0 ? 0 : (x0 > 255 ? 255 : x0);
    int y0 = (int)y0f; y0 = y0 < 0 ? 0 : (y0 > 255 ? 255 : y0);
    int x1 = x0 + 1 > 255 ? 255 : x0 + 1;
    int y1 = y0 + 1 > 255 ? 255 : y0 + 1;
    float w00 = (1.f - wx) * (1.f - wy), w01 = wx * (1.f - wy);
    float w10 = (1.f - wx) * wy, w11 = wx * wy;
    int i00 = y0 * 256 + x0, i01 = y0 * 256 + x1;
    int i10 = y1 * 256 + x0, i11 = y1 * 256 + x1;
    float b[8];
#pragma unroll
    for (int j = 0; j < 8; ++j) {
      const float* base = PL[p] + (size_t)(t * 8 + j) * 65536u;
      b[j] = w00 * base[i00] + w01 * base[i01] + w10 * base[i10] + w11 * base[i11];
    }
    float csv = (ax + 1.f) * 0.5f * 255.f;
    float theta1 = 6.283185307179586f * csv * (1.f / 256.f);
    float partial = is_re ? b[0] : 0.f;
#pragma unroll
    for (int r = 1; r < 8; ++r) {
      float thr = theta1 * (float)(1 << (r - 1));
      float s, c;
      __sincosf(thr, &s, &c);
      partial += b[r] * (is_re ? c : s);
    }
    float other = __shfl_xor(partial, 16);
    acc += partial - other;
  }
  if (is_re) out[n * 16 + t] = acc;
}

extern "C" void kernel_launch(void* const* d_in, const int* in_sizes, int n_in,
                              void* d_out, int out_size, void* d_ws, size_t ws_size,
                              hipStream_t stream) {
  const float* inputs = (const float*)d_in[0];
  const float* Pu = (const float*)d_in[1];
  const float* Pv = (const float*)d_in[2];
  const float* Pw = (const float*)d_in[3];
  float* out = (float*)d_out;

  if (ws_size >= WS_NEED) {
    char* ws = (char*)d_ws;
    __half*   T       = (__half*)ws;
    float4*   sortedC = (float4*)(ws + OFF_SORTED);
    __half*   partial = (__half*)(ws + OFF_PARTIAL);
    unsigned* hist    = (unsigned*)(ws + OFF_HIST);

    {
      dim3 tg(64, 16, 3);
      PREFFFT_trans_k<<<tg, 256, 0, stream>>>(Pu, Pv, Pw, T);
    }
    hipMemsetAsync(hist, 0, (size_t)3 * 65536 * 4, stream);
    PREFFFT_hist_k<<<NPTS / 256, 256, 0, stream>>>(inputs, hist);
    PREFFFT_scan_k<<<3, 1024, 0, stream>>>(hist);
    PREFFFT_scat_k<<<NPTS / 256, 256, 0, stream>>>(inputs, hist, sortedC);
    {
      dim3 tg(NPTS / 32, 3);
      PREFFFT_samp_k<<<tg, 256, 0, stream>>>(sortedC, T, partial);
    }
    PREFFFT_red_k<<<2048, 256, 0, stream>>>(partial, out);
  } else {
    PREFFFT_fallback_k<<<NPTS / 8, 256, 0, stream>>>(inputs, Pu, Pv, Pw, out);
  }
}

// Round 9
// 242.297 us; speedup vs baseline: 1.5391x; 1.5391x over previous
//
#include <hip/hip_runtime.h>
#include <hip/hip_fp16.h>
#include <math.h>

#define NPTS 262144
#define PLANE_ELEMS 16777216u   // 256*256*256

typedef __attribute__((ext_vector_type(4))) float f4;
typedef __attribute__((ext_vector_type(4))) unsigned int u4;

// ws layout (bytes):
//   [0, 96 MB)        : fp16 transposed planes (3 x 32 MB), layout [hw][c=256]
//   +12.58 MB         : sortedC float4[3][NPTS] (c0,c1,c2,bits(n))
//   +25.17 MB         : partial fp16[3][NPTS][16]
//   +0.75 MB          : hist unsigned[3][65536]
#define OFF_SORTED   (3ull * PLANE_ELEMS * 2ull)
#define OFF_PARTIAL  (OFF_SORTED + (size_t)3 * NPTS * 16)
#define OFF_HIST     (OFF_PARTIAL + (size_t)3 * NPTS * 16 * 2)
#define WS_NEED      (OFF_HIST + (size_t)3 * 65536 * 4)

__device__ __forceinline__ void plane_xy(int p, float c0, float c1, float c2,
                                         float& gx, float& gy, float& ax) {
  if (p == 0)      { gx = c1; gy = c2; ax = c0; }
  else if (p == 1) { gx = c0; gy = c2; ax = c1; }
  else             { gx = c0; gy = c1; ax = c2; }
}

__device__ __forceinline__ int cell_of(float g) {
  float i = (g + 1.f) * 0.5f * 255.f;
  int x0 = (int)floorf(i);
  return x0 < 0 ? 0 : (x0 > 255 ? 255 : x0);
}

// ---------------------------------------------------------------------------
// Transpose + convert: (C, H*W) fp32 -> (H*W, C) fp16.  [round-7 verified
// kernel; ONLY change: grid flattened so the 4 c-blocks of one hw-span are
// adjacent in dispatch order -> their 4 x 128B write pieces of each texel
// land near-simultaneously (DRAM page coalescing on the write stream).]
// Tile: 64 c x 128 hw. grid (2048, 1, 3): cb = x&3, hwb = x>>2. LDS 18 KB.
// ---------------------------------------------------------------------------
__global__ __launch_bounds__(256) void PREFFFT_trans_k(
    const float* __restrict__ Pu, const float* __restrict__ Pv,
    const float* __restrict__ Pw, __half* __restrict__ dst0) {
  __shared__ unsigned tile[128 * 36];  // 18 KB
  const float* src = blockIdx.z == 0 ? Pu : (blockIdx.z == 1 ? Pv : Pw);
  __half* dst = dst0 + (size_t)blockIdx.z * PLANE_ELEMS;
  const unsigned hw0 = (blockIdx.x >> 2) * 128u;
  const unsigned c0 = (blockIdx.x & 3u) * 64u;
  const int tid = threadIdx.x;

  // ---- read phase: 8 independent float4 loads/thread, issued up front ----
  f4 va[4], vb[4];
#pragma unroll
  for (int j = 0; j < 4; ++j) {
    int idx = j * 256 + tid;  // 0..1023
    int rp = idx >> 5;        // 0..31 : c-pair index (c = c0 + 2rp, +1)
    int q = idx & 31;         // 0..31 : f4 column (hw = 4q..4q+3)
    const float* base = src + (size_t)(c0 + 2 * rp) * 65536u + hw0 + 4 * q;
    va[j] = *(const f4*)(base);
    vb[j] = *(const f4*)(base + 65536);
  }
  // ---- convert + swizzled LDS write (2 lanes/bank on all 32 banks: free) --
#pragma unroll
  for (int j = 0; j < 4; ++j) {
    int idx = j * 256 + tid;
    int rp = idx >> 5;
    int q = idx & 31;
#pragma unroll
    for (int k = 0; k < 4; ++k) {
      int hw = 4 * q + k;
      __half2 h = __floats2half2_rn(va[j][k], vb[j][k]);
      tile[hw * 36 + (rp ^ (hw >> 3))] = *(unsigned*)&h;
    }
  }
  __syncthreads();
  // ---- write phase: b128 LDS reads + 16B global stores ----
  int seg = tid & 7;          // 0..7 : 16B segment within the 128B c-slice
#pragma unroll
  for (int jj = 0; jj < 4; ++jj) {
    int hw = jj * 32 + (tid >> 3);
    int s = hw >> 3;          // wave-uniform
    u4 v = *(const u4*)(tile + hw * 36 + 4 * ((seg ^ (s >> 2)) & 7));
    u4 o;
    switch (s & 3) {          // wave-uniform switch: unpermute low2 of rp
      case 0: o = v; break;
      case 1: o = u4{v.y, v.x, v.w, v.z}; break;
      case 2: o = u4{v.z, v.w, v.x, v.y}; break;
      default: o = u4{v.w, v.z, v.y, v.x}; break;
    }
    *(u4*)((char*)dst + ((size_t)(hw0 + hw) * 256u + c0) * 2u + seg * 16u) = o;
  }
}

// ---------------------------------------------------------------------------
// Counting sort: histogram / scan / scatter (16-bit plane-cell keys).
// ---------------------------------------------------------------------------
__global__ __launch_bounds__(256) void PREFFFT_hist_k(
    const float* __restrict__ inputs, unsigned* __restrict__ hist) {
  int n = blockIdx.x * 256 + threadIdx.x;
  if (n >= NPTS) return;
  float c0 = inputs[n * 3 + 0], c1 = inputs[n * 3 + 1], c2 = inputs[n * 3 + 2];
#pragma unroll
  for (int p = 0; p < 3; ++p) {
    float gx, gy, ax;
    plane_xy(p, c0, c1, c2, gx, gy, ax);
    int key = (cell_of(gy) << 8) | cell_of(gx);
    atomicAdd(&hist[p * 65536 + key], 1u);
  }
}

__global__ __launch_bounds__(1024) void PREFFFT_scan_k(unsigned* __restrict__ hist) {
  __shared__ unsigned part[1024];
  unsigned* h = hist + (size_t)blockIdx.x * 65536;
  int t = threadIdx.x;
  unsigned s = 0;
#pragma unroll 8
  for (int i = 0; i < 64; ++i) s += h[t * 64 + i];
  part[t] = s;
  __syncthreads();
  for (int off = 1; off < 1024; off <<= 1) {
    unsigned v = (t >= off) ? part[t - off] : 0u;
    __syncthreads();
    part[t] += v;
    __syncthreads();
  }
  unsigned run = (t == 0) ? 0u : part[t - 1];
#pragma unroll 8
  for (int i = 0; i < 64; ++i) {
    unsigned c = h[t * 64 + i];
    h[t * 64 + i] = run;
    run += c;
  }
}

__global__ __launch_bounds__(256) void PREFFFT_scat_k(
    const float* __restrict__ inputs, unsigned* __restrict__ hist,
    float4* __restrict__ sortedC) {
  int n = blockIdx.x * 256 + threadIdx.x;
  if (n >= NPTS) return;
  float c0 = inputs[n * 3 + 0], c1 = inputs[n * 3 + 1], c2 = inputs[n * 3 + 2];
#pragma unroll
  for (int p = 0; p < 3; ++p) {
    float gx, gy, ax;
    plane_xy(p, c0, c1, c2, gx, gy, ax);
    int key = (cell_of(gy) << 8) | cell_of(gx);
    unsigned pos = atomicAdd(&hist[p * 65536 + key], 1u);
    sortedC[(size_t)p * NPTS + pos] =
        make_float4(c0, c1, c2, __uint_as_float((unsigned)n));
  }
}

// ---------------------------------------------------------------------------
// Sample pass: 8 lanes/point. Lane t owns re-ch2 {2t,2t+1} (plane ch t*16..+15)
// and im-ch2 {16+2t,16+2t+1} (plane ch 128+t*16..+15). Bilinear in packed
// fp16 (v_pk_fma_f16); Fourier dots in f32 with shared double-angle trig.
// Writes fp16 partials (4B/lane, 32B/point, by original index n).
// grid (NPTS/32, 3), block 256.  [round-7 verified version, T = [hw][c]]
// ---------------------------------------------------------------------------
__global__ __launch_bounds__(256) void PREFFFT_samp_k(
    const float4* __restrict__ sortedC, const __half* __restrict__ T,
    __half* __restrict__ partial) {
  int p = blockIdx.y;
  int bx = blockIdx.x;                      // 0..8191
  int lbx = (bx & 7) * 1024 + (bx >> 3);    // XCD-contiguous chunks
  int slot = lbx * 32 + ((int)threadIdx.x >> 3);
  int t = threadIdx.x & 7;

  float4 sc = sortedC[(size_t)p * NPTS + slot];
  unsigned n = __float_as_uint(sc.w);
  float gx, gy, ax;
  plane_xy(p, sc.x, sc.y, sc.z, gx, gy, ax);

  float ix = (gx + 1.f) * 0.5f * 255.f;
  float iy = (gy + 1.f) * 0.5f * 255.f;
  float x0f = floorf(ix), y0f = floorf(iy);
  float wx = ix - x0f, wy = iy - y0f;
  int x0 = (int)x0f; x0 = x0 < 0 ? 0 : (x0 > 255 ? 255 : x0);
  int y0 = (int)y0f; y0 = y0 < 0 ? 0 : (y0 > 255 ? 255 : y0);
  int x1 = x0 + 1 > 255 ? 255 : x0 + 1;
  int y1 = y0 + 1 > 255 ? 255 : y0 + 1;
  float w00 = (1.f - wx) * (1.f - wy);
  float w01 = wx * (1.f - wy);
  float w10 = (1.f - wx) * wy;
  float w11 = wx * wy;

  const __half* __restrict__ P = T + (size_t)p * PLANE_ELEMS;
  int r00 = (y0 * 256 + x0) * 256, r01 = (y0 * 256 + x1) * 256;
  int r10 = (y1 * 256 + x0) * 256, r11 = (y1 * 256 + x1) * 256;
  int ore = t * 16;         // re channels t*16..t*16+15
  int oim = 128 + t * 16;   // im channels

  // 16 x 16B loads (4 corners x {re_lo, re_hi, im_lo, im_hi})
  f4 a0 = *(const f4*)(P + r00 + ore),     a1 = *(const f4*)(P + r00 + ore + 8);
  f4 a2 = *(const f4*)(P + r00 + oim),     a3 = *(const f4*)(P + r00 + oim + 8);
  f4 b0 = *(const f4*)(P + r01 + ore),     b1 = *(const f4*)(P + r01 + ore + 8);
  f4 b2 = *(const f4*)(P + r01 + oim),     b3 = *(const f4*)(P + r01 + oim + 8);
  f4 c0v = *(const f4*)(P + r10 + ore),    c1v = *(const f4*)(P + r10 + ore + 8);
  f4 c2v = *(const f4*)(P + r10 + oim),    c3v = *(const f4*)(P + r10 + oim + 8);
  f4 d0 = *(const f4*)(P + r11 + ore),     d1 = *(const f4*)(P + r11 + ore + 8);
  f4 d2 = *(const f4*)(P + r11 + oim),     d3 = *(const f4*)(P + r11 + oim + 8);

  __half2 hw00 = __float2half2_rn(w00), hw01 = __float2half2_rn(w01);
  __half2 hw10 = __float2half2_rn(w10), hw11 = __float2half2_rn(w11);

  // bilinear blend in packed fp16: 16 h2 outputs (8 re, 8 im)
  __half2 bre[8], bim[8];
#pragma unroll
  for (int q = 0; q < 4; ++q) {
    __half2 v;
    v = __hmul2(((const __half2*)&a0)[q], hw00);
    v = __hfma2(((const __half2*)&b0)[q],  hw01, v);
    v = __hfma2(((const __half2*)&c0v)[q], hw10, v);
    bre[q] = __hfma2(((const __half2*)&d0)[q], hw11, v);

    v = __hmul2(((const __half2*)&a1)[q], hw00);
    v = __hfma2(((const __half2*)&b1)[q],  hw01, v);
    v = __hfma2(((const __half2*)&c1v)[q], hw10, v);
    bre[q + 4] = __hfma2(((const __half2*)&d1)[q], hw11, v);

    v = __hmul2(((const __half2*)&a2)[q], hw00);
    v = __hfma2(((const __half2*)&b2)[q],  hw01, v);
    v = __hfma2(((const __half2*)&c2v)[q], hw10, v);
    bim[q] = __hfma2(((const __half2*)&d2)[q], hw11, v);

    v = __hmul2(((const __half2*)&a3)[q], hw00);
    v = __hfma2(((const __half2*)&b3)[q],  hw01, v);
    v = __hfma2(((const __half2*)&c3v)[q], hw10, v);
    bim[q + 4] = __hfma2(((const __half2*)&d3)[q], hw11, v);
  }

  // unpack to f32: fre[0..7] = ch2=2t r=0..7; fre[8..15] = ch2=2t+1
  float fre[16], fim[16];
#pragma unroll
  for (int q = 0; q < 8; ++q) {
    float2 vr = __half22float2(bre[q]);
    float2 vi = __half22float2(bim[q]);
    fre[2 * q] = vr.x; fre[2 * q + 1] = vr.y;
    fim[2 * q] = vi.x; fim[2 * q + 1] = vi.y;
  }

  // Fourier: theta_r = theta1 * 2^(r-1); r=0 term cos=1 / sin=0.
  float cs = (ax + 1.f) * 0.5f * 255.f;
  float th = 6.283185307179586f * cs * (1.f / 256.f);
  float s, c;
  __sincosf(th, &s, &c);
  float aR0 = fre[0], aR1 = fre[8];
  float aI0 = 0.f,    aI1 = 0.f;
#pragma unroll
  for (int r = 1; r < 8; ++r) {
    aR0 += fre[r] * c;     aR1 += fre[8 + r] * c;
    aI0 += fim[r] * s;     aI1 += fim[8 + r] * s;
    if (r < 7) {
      float c2 = c + c;
      float cn = c2 * c - 1.f;   // cos(2a) = 2cos^2 - 1
      s = c2 * s;                // sin(2a) = 2 sin cos
      c = cn;
    }
  }

  *(__half2*)(partial + ((size_t)p * NPTS + n) * 16 + 2 * t) =
      __floats2half2_rn(aR0 - aI0, aR1 - aI1);
}

// ---------------------------------------------------------------------------
// Reduce: out = sum of 3 fp16 partials, f32 output. 8 outputs/thread.
// ---------------------------------------------------------------------------
__global__ __launch_bounds__(256) void PREFFFT_red_k(
    const __half* __restrict__ part, float* __restrict__ out) {
  size_t i = (size_t)blockIdx.x * 256 + threadIdx.x;  // < 524288
  const size_t PS = (size_t)NPTS * 16;
  union H8 { u4 v; __half2 h[4]; };
  H8 a, b, c;
  a.v = *(const u4*)(part + i * 8);
  b.v = *(const u4*)(part + PS + i * 8);
  c.v = *(const u4*)(part + 2 * PS + i * 8);
  f4 o0, o1;
#pragma unroll
  for (int k = 0; k < 4; ++k) {
    float2 fa = __half22float2(a.h[k]);
    float2 fb = __half22float2(b.h[k]);
    float2 fc = __half22float2(c.h[k]);
    float lo = fa.x + fb.x + fc.x;
    float hi = fa.y + fb.y + fc.y;
    if (k < 2) { o0[2 * k] = lo; o0[2 * k + 1] = hi; }
    else       { o1[2 * (k - 2)] = lo; o1[2 * (k - 2) + 1] = hi; }
  }
  ((f4*)out)[i * 2] = o0;
  ((f4*)out)[i * 2 + 1] = o1;
}

// ---------------------------------------------------------------------------
// Fallback (ws too small): original (C,H,W) fp32 direct, slow but correct.
// ---------------------------------------------------------------------------
__global__ __launch_bounds__(256) void PREFFFT_fallback_k(
    const float* __restrict__ inputs, const float* __restrict__ Tu,
    const float* __restrict__ Tv, const float* __restrict__ Tw,
    float* __restrict__ out) {
  int gtid = blockIdx.x * 256 + threadIdx.x;
  int n = gtid >> 5;
  int t = threadIdx.x & 31;
  const bool is_re = t < 16;
  float c0 = inputs[n * 3 + 0], c1 = inputs[n * 3 + 1], c2 = inputs[n * 3 + 2];
  const float* PL[3] = {Tu, Tv, Tw};
  float acc = 0.f;
#pragma unroll
  for (int p = 0; p < 3; ++p) {
    float gx, gy, ax;
    plane_xy(p, c0, c1, c2, gx, gy, ax);
    float ix = (gx + 1.f) * 0.5f * 255.f;
    float iy = (gy + 1.f) * 0.5f * 255.f;
    float x0f = floorf(ix), y0f = floorf(iy);
    float wx = ix - x0f, wy = iy - y0f;
    int x0 = (int)x0f; x0 = x0 < 0 ? 0 : (x0 > 255 ? 255 : x0);
    int y0 = (int)y0f; y0 = y0 < 0 ? 0 : (y0 > 255 ? 255 : y0);
    int x1 = x0 + 1 > 255 ? 255 : x0 + 1;
    int y1 = y0 + 1 > 255 ? 255 : y0 + 1;
    float w00 = (1.f - wx) * (1.f - wy), w01 = wx * (1.f - wy);
    float w10 = (1.f - wx) * wy, w11 = wx * wy;
    int i00 = y0 * 256 + x0, i01 = y0 * 256 + x1;
    int i10 = y1 * 256 + x0, i11 = y1 * 256 + x1;
    float b[8];
#pragma unroll
    for (int j = 0; j < 8; ++j) {
      const float* base = PL[p] + (size_t)(t * 8 + j) * 65536u;
      b[j] = w00 * base[i00] + w01 * base[i01] + w10 * base[i10] + w11 * base[i11];
    }
    float csv = (ax + 1.f) * 0.5f * 255.f;
    float theta1 = 6.283185307179586f * csv * (1.f / 256.f);
    float partial = is_re ? b[0] : 0.f;
#pragma unroll
    for (int r = 1; r < 8; ++r) {
      float thr = theta1 * (float)(1 << (r - 1));
      float s, c;
      __sincosf(thr, &s, &c);
      partial += b[r] * (is_re ? c : s);
    }
    float other = __shfl_xor(partial, 16);
    acc += partial - other;
  }
  if (is_re) out[n * 16 + t] = acc;
}

extern "C" void kernel_launch(void* const* d_in, const int* in_sizes, int n_in,
                              void* d_out, int out_size, void* d_ws, size_t ws_size,
                              hipStream_t stream) {
  const float* inputs = (const float*)d_in[0];
  const float* Pu = (const float*)d_in[1];
  const float* Pv = (const float*)d_in[2];
  const float* Pw = (const float*)d_in[3];
  float* out = (float*)d_out;

  if (ws_size >= WS_NEED) {
    char* ws = (char*)d_ws;
    __half*   T       = (__half*)ws;
    float4*   sortedC = (float4*)(ws + OFF_SORTED);
    __half*   partial = (__half*)(ws + OFF_PARTIAL);
    unsigned* hist    = (unsigned*)(ws + OFF_HIST);

    {
      dim3 tg(2048, 1, 3);   // x = hwb*4 + cb : c-blocks of one hw-span adjacent
      PREFFFT_trans_k<<<tg, 256, 0, stream>>>(Pu, Pv, Pw, T);
    }
    hipMemsetAsync(hist, 0, (size_t)3 * 65536 * 4, stream);
    PREFFFT_hist_k<<<NPTS / 256, 256, 0, stream>>>(inputs, hist);
    PREFFFT_scan_k<<<3, 1024, 0, stream>>>(hist);
    PREFFFT_scat_k<<<NPTS / 256, 256, 0, stream>>>(inputs, hist, sortedC);
    {
      dim3 tg(NPTS / 32, 3);
      PREFFFT_samp_k<<<tg, 256, 0, stream>>>(sortedC, T, partial);
    }
    PREFFFT_red_k<<<2048, 256, 0, stream>>>(partial, out);
  } else {
    PREFFFT_fallback_k<<<NPTS / 8, 256, 0, stream>>>(inputs, Pu, Pv, Pw, out);
  }
}

// Round 10
// 228.341 us; speedup vs baseline: 1.6332x; 1.0611x over previous
//
#include <hip/hip_runtime.h>
#include <hip/hip_fp16.h>
#include <math.h>

#define NPTS 262144
#define PLANE_ELEMS 16777216u   // 256*256*256

typedef __attribute__((ext_vector_type(4))) float f4;
typedef __attribute__((ext_vector_type(4))) unsigned int u4;

// ws layout (bytes):
//   [0, 96 MB)        : fp16 transposed planes (3 x 32 MB), layout [hw][c=256]
//   +12.58 MB         : sortedC float4[3][NPTS] (gx,gy,ax,bits(n)) pre-swizzled
//   +25.17 MB         : partial fp16[3][NPTS][16]
//   +0.75 MB          : hist unsigned[3][65536]
#define OFF_SORTED   (3ull * PLANE_ELEMS * 2ull)
#define OFF_PARTIAL  (OFF_SORTED + (size_t)3 * NPTS * 16)
#define OFF_HIST     (OFF_PARTIAL + (size_t)3 * NPTS * 16 * 2)
#define WS_NEED      (OFF_HIST + (size_t)3 * 65536 * 4)

__device__ __forceinline__ void plane_xy(int p, float c0, float c1, float c2,
                                         float& gx, float& gy, float& ax) {
  if (p == 0)      { gx = c1; gy = c2; ax = c0; }
  else if (p == 1) { gx = c0; gy = c2; ax = c1; }
  else             { gx = c0; gy = c1; ax = c2; }
}

__device__ __forceinline__ int cell_of(float g) {
  float i = (g + 1.f) * 0.5f * 255.f;
  int x0 = (int)floorf(i);
  return x0 < 0 ? 0 : (x0 > 255 ? 255 : x0);
}

// ---------------------------------------------------------------------------
// Transpose + convert: (C, H*W) fp32 -> (H*W, C) fp16.
// R10: 4 tiles/block with register ping-pong pipeline — tile i+1's 8 loads
// are issued BEFORE tile i's convert/LDS/store phases, so global loads stay
// in flight across the store phase (kills the per-block pipeline tail).
// Reads are nontemporal (planes are read exactly once -> keep L2/L3 for T).
// Tile: 64c x 128hw, LDS 18 KB, same verified swizzle as R7.
// grid (128, 4, 3), block 256.
// ---------------------------------------------------------------------------
__device__ __forceinline__ void trans_load(const float* __restrict__ src,
                                           unsigned c0, unsigned hw0, int tid,
                                           f4 (&va)[4], f4 (&vb)[4]) {
#pragma unroll
  for (int j = 0; j < 4; ++j) {
    int idx = j * 256 + tid;  // 0..1023
    int rp = idx >> 5;        // 0..31 : c-pair index
    int q = idx & 31;         // 0..31 : f4 column (hw = 4q..4q+3)
    const f4* base = (const f4*)(src + (size_t)(c0 + 2 * rp) * 65536u + hw0 + 4 * q);
    va[j] = __builtin_nontemporal_load(base);
    vb[j] = __builtin_nontemporal_load(base + 16384);  // +65536 floats
  }
}

__device__ __forceinline__ void trans_proc(unsigned* tile, __half* dst,
                                           unsigned c0, unsigned hw0, int tid,
                                           f4 (&va)[4], f4 (&vb)[4]) {
#pragma unroll
  for (int j = 0; j < 4; ++j) {
    int idx = j * 256 + tid;
    int rp = idx >> 5;
    int q = idx & 31;
#pragma unroll
    for (int k = 0; k < 4; ++k) {
      int hw = 4 * q + k;
      __half2 h = __floats2half2_rn(va[j][k], vb[j][k]);
      tile[hw * 36 + (rp ^ (hw >> 3))] = *(unsigned*)&h;
    }
  }
  __syncthreads();
  int seg = tid & 7;
#pragma unroll
  for (int jj = 0; jj < 4; ++jj) {
    int hw = jj * 32 + (tid >> 3);
    int s = hw >> 3;          // wave-uniform
    u4 v = *(const u4*)(tile + hw * 36 + 4 * ((seg ^ (s >> 2)) & 7));
    u4 o;
    switch (s & 3) {          // wave-uniform unpermute of low2 of rp
      case 0: o = v; break;
      case 1: o = u4{v.y, v.x, v.w, v.z}; break;
      case 2: o = u4{v.z, v.w, v.x, v.y}; break;
      default: o = u4{v.w, v.z, v.y, v.x}; break;
    }
    *(u4*)((char*)dst + ((size_t)(hw0 + hw) * 256u + c0) * 2u + seg * 16u) = o;
  }
  __syncthreads();  // protect LDS reuse by next tile
}

__global__ __launch_bounds__(256) void PREFFFT_trans_k(
    const float* __restrict__ Pu, const float* __restrict__ Pv,
    const float* __restrict__ Pw, __half* __restrict__ dst0) {
  __shared__ unsigned tile[128 * 36];  // 18 KB
  const float* src = blockIdx.z == 0 ? Pu : (blockIdx.z == 1 ? Pv : Pw);
  __half* dst = dst0 + (size_t)blockIdx.z * PLANE_ELEMS;
  const unsigned hwbase = blockIdx.x * 512u;   // 4 tiles of 128 hw
  const unsigned c0 = blockIdx.y * 64u;
  const int tid = threadIdx.x;

  f4 vaA[4], vbA[4], vaB[4], vbB[4];
  trans_load(src, c0, hwbase, tid, vaA, vbA);
  // tile 0: prefetch 1 into B, process A
  trans_load(src, c0, hwbase + 128u, tid, vaB, vbB);
  trans_proc(tile, dst, c0, hwbase, tid, vaA, vbA);
  // tile 1: prefetch 2 into A, process B
  trans_load(src, c0, hwbase + 256u, tid, vaA, vbA);
  trans_proc(tile, dst, c0, hwbase + 128u, tid, vaB, vbB);
  // tile 2: prefetch 3 into B, process A
  trans_load(src, c0, hwbase + 384u, tid, vaB, vbB);
  trans_proc(tile, dst, c0, hwbase + 256u, tid, vaA, vbA);
  // tile 3: process B
  trans_proc(tile, dst, c0, hwbase + 384u, tid, vaB, vbB);
}

// ---------------------------------------------------------------------------
// Counting sort: histogram / scan / scatter (16-bit plane-cell keys).
// ---------------------------------------------------------------------------
__global__ __launch_bounds__(256) void PREFFFT_hist_k(
    const float* __restrict__ inputs, unsigned* __restrict__ hist) {
  int n = blockIdx.x * 256 + threadIdx.x;
  if (n >= NPTS) return;
  float c0 = inputs[n * 3 + 0], c1 = inputs[n * 3 + 1], c2 = inputs[n * 3 + 2];
#pragma unroll
  for (int p = 0; p < 3; ++p) {
    float gx, gy, ax;
    plane_xy(p, c0, c1, c2, gx, gy, ax);
    int key = (cell_of(gy) << 8) | cell_of(gx);
    atomicAdd(&hist[p * 65536 + key], 1u);
  }
}

__global__ __launch_bounds__(1024) void PREFFFT_scan_k(unsigned* __restrict__ hist) {
  __shared__ unsigned part[1024];
  unsigned* h = hist + (size_t)blockIdx.x * 65536;
  int t = threadIdx.x;
  unsigned s = 0;
#pragma unroll 8
  for (int i = 0; i < 64; ++i) s += h[t * 64 + i];
  part[t] = s;
  __syncthreads();
  for (int off = 1; off < 1024; off <<= 1) {
    unsigned v = (t >= off) ? part[t - off] : 0u;
    __syncthreads();
    part[t] += v;
    __syncthreads();
  }
  unsigned run = (t == 0) ? 0u : part[t - 1];
#pragma unroll 8
  for (int i = 0; i < 64; ++i) {
    unsigned c = h[t * 64 + i];
    h[t * 64 + i] = run;
    run += c;
  }
}

__global__ __launch_bounds__(256) void PREFFFT_scat_k(
    const float* __restrict__ inputs, unsigned* __restrict__ hist,
    float4* __restrict__ sortedC) {
  int n = blockIdx.x * 256 + threadIdx.x;
  if (n >= NPTS) return;
  float c0 = inputs[n * 3 + 0], c1 = inputs[n * 3 + 1], c2 = inputs[n * 3 + 2];
#pragma unroll
  for (int p = 0; p < 3; ++p) {
    float gx, gy, ax;
    plane_xy(p, c0, c1, c2, gx, gy, ax);
    int key = (cell_of(gy) << 8) | cell_of(gx);
    unsigned pos = atomicAdd(&hist[p * 65536 + key], 1u);
    // store pre-swizzled plane coords: samp doesn't need plane_xy
    sortedC[(size_t)p * NPTS + pos] =
        make_float4(gx, gy, ax, __uint_as_float((unsigned)n));
  }
}

// ---------------------------------------------------------------------------
// Sample pass: 8 lanes/point. Lane t owns re-ch2 {2t,2t+1} (plane ch t*16..+15)
// and im-ch2 {16+2t,16+2t+1} (plane ch 128+t*16..+15). Bilinear in packed
// fp16 (v_pk_fma_f16); Fourier dots in f32 with shared double-angle trig.
// Writes fp16 partials (4B/lane, 32B/point, by original index n).
// grid (NPTS/32, 3), block 256.  [R7-verified; coords now pre-swizzled]
// ---------------------------------------------------------------------------
__global__ __launch_bounds__(256) void PREFFFT_samp_k(
    const float4* __restrict__ sortedC, const __half* __restrict__ T,
    __half* __restrict__ partial) {
  int p = blockIdx.y;
  int bx = blockIdx.x;                      // 0..8191
  int lbx = (bx & 7) * 1024 + (bx >> 3);    // XCD-contiguous chunks
  int slot = lbx * 32 + ((int)threadIdx.x >> 3);
  int t = threadIdx.x & 7;

  float4 sc = sortedC[(size_t)p * NPTS + slot];
  unsigned n = __float_as_uint(sc.w);
  float gx = sc.x, gy = sc.y, ax = sc.z;

  float ix = (gx + 1.f) * 0.5f * 255.f;
  float iy = (gy + 1.f) * 0.5f * 255.f;
  float x0f = floorf(ix), y0f = floorf(iy);
  float wx = ix - x0f, wy = iy - y0f;
  int x0 = (int)x0f; x0 = x0 < 0 ? 0 : (x0 > 255 ? 255 : x0);
  int y0 = (int)y0f; y0 = y0 < 0 ? 0 : (y0 > 255 ? 255 : y0);
  int x1 = x0 + 1 > 255 ? 255 : x0 + 1;
  int y1 = y0 + 1 > 255 ? 255 : y0 + 1;
  float w00 = (1.f - wx) * (1.f - wy);
  float w01 = wx * (1.f - wy);
  float w10 = (1.f - wx) * wy;
  float w11 = wx * wy;

  const __half* __restrict__ P = T + (size_t)p * PLANE_ELEMS;
  int r00 = (y0 * 256 + x0) * 256, r01 = (y0 * 256 + x1) * 256;
  int r10 = (y1 * 256 + x0) * 256, r11 = (y1 * 256 + x1) * 256;
  int ore = t * 16;         // re channels t*16..t*16+15
  int oim = 128 + t * 16;   // im channels

  // 16 x 16B loads (4 corners x {re_lo, re_hi, im_lo, im_hi})
  f4 a0 = *(const f4*)(P + r00 + ore),     a1 = *(const f4*)(P + r00 + ore + 8);
  f4 a2 = *(const f4*)(P + r00 + oim),     a3 = *(const f4*)(P + r00 + oim + 8);
  f4 b0 = *(const f4*)(P + r01 + ore),     b1 = *(const f4*)(P + r01 + ore + 8);
  f4 b2 = *(const f4*)(P + r01 + oim),     b3 = *(const f4*)(P + r01 + oim + 8);
  f4 c0v = *(const f4*)(P + r10 + ore),    c1v = *(const f4*)(P + r10 + ore + 8);
  f4 c2v = *(const f4*)(P + r10 + oim),    c3v = *(const f4*)(P + r10 + oim + 8);
  f4 d0 = *(const f4*)(P + r11 + ore),     d1 = *(const f4*)(P + r11 + ore + 8);
  f4 d2 = *(const f4*)(P + r11 + oim),     d3 = *(const f4*)(P + r11 + oim + 8);

  __half2 hw00 = __float2half2_rn(w00), hw01 = __float2half2_rn(w01);
  __half2 hw10 = __float2half2_rn(w10), hw11 = __float2half2_rn(w11);

  // bilinear blend in packed fp16: 16 h2 outputs (8 re, 8 im)
  __half2 bre[8], bim[8];
#pragma unroll
  for (int q = 0; q < 4; ++q) {
    __half2 v;
    v = __hmul2(((const __half2*)&a0)[q], hw00);
    v = __hfma2(((const __half2*)&b0)[q],  hw01, v);
    v = __hfma2(((const __half2*)&c0v)[q], hw10, v);
    bre[q] = __hfma2(((const __half2*)&d0)[q], hw11, v);

    v = __hmul2(((const __half2*)&a1)[q], hw00);
    v = __hfma2(((const __half2*)&b1)[q],  hw01, v);
    v = __hfma2(((const __half2*)&c1v)[q], hw10, v);
    bre[q + 4] = __hfma2(((const __half2*)&d1)[q], hw11, v);

    v = __hmul2(((const __half2*)&a2)[q], hw00);
    v = __hfma2(((const __half2*)&b2)[q],  hw01, v);
    v = __hfma2(((const __half2*)&c2v)[q], hw10, v);
    bim[q] = __hfma2(((const __half2*)&d2)[q], hw11, v);

    v = __hmul2(((const __half2*)&a3)[q], hw00);
    v = __hfma2(((const __half2*)&b3)[q],  hw01, v);
    v = __hfma2(((const __half2*)&c3v)[q], hw10, v);
    bim[q + 4] = __hfma2(((const __half2*)&d3)[q], hw11, v);
  }

  // unpack to f32: fre[0..7] = ch2=2t r=0..7; fre[8..15] = ch2=2t+1
  float fre[16], fim[16];
#pragma unroll
  for (int q = 0; q < 8; ++q) {
    float2 vr = __half22float2(bre[q]);
    float2 vi = __half22float2(bim[q]);
    fre[2 * q] = vr.x; fre[2 * q + 1] = vr.y;
    fim[2 * q] = vi.x; fim[2 * q + 1] = vi.y;
  }

  // Fourier: theta_r = theta1 * 2^(r-1); r=0 term cos=1 / sin=0.
  float cs = (ax + 1.f) * 0.5f * 255.f;
  float th = 6.283185307179586f * cs * (1.f / 256.f);
  float s, c;
  __sincosf(th, &s, &c);
  float aR0 = fre[0], aR1 = fre[8];
  float aI0 = 0.f,    aI1 = 0.f;
#pragma unroll
  for (int r = 1; r < 8; ++r) {
    aR0 += fre[r] * c;     aR1 += fre[8 + r] * c;
    aI0 += fim[r] * s;     aI1 += fim[8 + r] * s;
    if (r < 7) {
      float c2 = c + c;
      float cn = c2 * c - 1.f;   // cos(2a) = 2cos^2 - 1
      s = c2 * s;                // sin(2a) = 2 sin cos
      c = cn;
    }
  }

  *(__half2*)(partial + ((size_t)p * NPTS + n) * 16 + 2 * t) =
      __floats2half2_rn(aR0 - aI0, aR1 - aI1);
}

// ---------------------------------------------------------------------------
// Reduce: out = sum of 3 fp16 partials, f32 output. 8 outputs/thread.
// ---------------------------------------------------------------------------
__global__ __launch_bounds__(256) void PREFFFT_red_k(
    const __half* __restrict__ part, float* __restrict__ out) {
  size_t i = (size_t)blockIdx.x * 256 + threadIdx.x;  // < 524288
  const size_t PS = (size_t)NPTS * 16;
  union H8 { u4 v; __half2 h[4]; };
  H8 a, b, c;
  a.v = *(const u4*)(part + i * 8);
  b.v = *(const u4*)(part + PS + i * 8);
  c.v = *(const u4*)(part + 2 * PS + i * 8);
  f4 o0, o1;
#pragma unroll
  for (int k = 0; k < 4; ++k) {
    float2 fa = __half22float2(a.h[k]);
    float2 fb = __half22float2(b.h[k]);
    float2 fc = __half22float2(c.h[k]);
    float lo = fa.x + fb.x + fc.x;
    float hi = fa.y + fb.y + fc.y;
    if (k < 2) { o0[2 * k] = lo; o0[2 * k + 1] = hi; }
    else       { o1[2 * (k - 2)] = lo; o1[2 * (k - 2) + 1] = hi; }
  }
  ((f4*)out)[i * 2] = o0;
  ((f4*)out)[i * 2 + 1] = o1;
}

// ---------------------------------------------------------------------------
// Fallback (ws too small): original (C,H,W) fp32 direct, slow but correct.
// ---------------------------------------------------------------------------
__global__ __launch_bounds__(256) void PREFFFT_fallback_k(
    const float* __restrict__ inputs, const float* __restrict__ Tu,
    const float* __restrict__ Tv, const float* __restrict__ Tw,
    float* __restrict__ out) {
  int gtid = blockIdx.x * 256 + threadIdx.x;
  int n = gtid >> 5;
  int t = threadIdx.x & 31;
  const bool is_re = t < 16;
  float c0 = inputs[n * 3 + 0], c1 = inputs[n * 3 + 1], c2 = inputs[n * 3 + 2];
  const float* PL[3] = {Tu, Tv, Tw};
  float acc = 0.f;
#pragma unroll
  for (int p = 0; p < 3; ++p) {
    float gx, gy, ax;
    plane_xy(p, c0, c1, c2, gx, gy, ax);
    float ix = (gx + 1.f) * 0.5f * 255.f;
    float iy = (gy + 1.f) * 0.5f * 255.f;
    float x0f = floorf(ix), y0f = floorf(iy);
    float wx = ix - x0f, wy = iy - y0f;
    int x0 = (int)x0f; x0 = x0 < 0 ? 0 : (x0 > 255 ? 255 : x0);
    int y0 = (int)y0f; y0 = y0 < 0 ? 0 : (y0 > 255 ? 255 : y0);
    int x1 = x0 + 1 > 255 ? 255 : x0 + 1;
    int y1 = y0 + 1 > 255 ? 255 : y0 + 1;
    float w00 = (1.f - wx) * (1.f - wy), w01 = wx * (1.f - wy);
    float w10 = (1.f - wx) * wy, w11 = wx * wy;
    int i00 = y0 * 256 + x0, i01 = y0 * 256 + x1;
    int i10 = y1 * 256 + x0, i11 = y1 * 256 + x1;
    float b[8];
#pragma unroll
    for (int j = 0; j < 8; ++j) {
      const float* base = PL[p] + (size_t)(t * 8 + j) * 65536u;
      b[j] = w00 * base[i00] + w01 * base[i01] + w10 * base[i10] + w11 * base[i11];
    }
    float csv = (ax + 1.f) * 0.5f * 255.f;
    float theta1 = 6.283185307179586f * csv * (1.f / 256.f);
    float partial = is_re ? b[0] : 0.f;
#pragma unroll
    for (int r = 1; r < 8; ++r) {
      float thr = theta1 * (float)(1 << (r - 1));
      float s, c;
      __sincosf(thr, &s, &c);
      partial += b[r] * (is_re ? c : s);
    }
    float other = __shfl_xor(partial, 16);
    acc += partial - other;
  }
  if (is_re) out[n * 16 + t] = acc;
}

extern "C" void kernel_launch(void* const* d_in, const int* in_sizes, int n_in,
                              void* d_out, int out_size, void* d_ws, size_t ws_size,
                              hipStream_t stream) {
  const float* inputs = (const float*)d_in[0];
  const float* Pu = (const float*)d_in[1];
  const float* Pv = (const float*)d_in[2];
  const float* Pw = (const float*)d_in[3];
  float* out = (float*)d_out;

  if (ws_size >= WS_NEED) {
    char* ws = (char*)d_ws;
    __half*   T       = (__half*)ws;
    float4*   sortedC = (float4*)(ws + OFF_SORTED);
    __half*   partial = (__half*)(ws + OFF_PARTIAL);
    unsigned* hist    = (unsigned*)(ws + OFF_HIST);

    {
      dim3 tg(128, 4, 3);   // 4 pipelined 64c x 128hw tiles per block
      PREFFFT_trans_k<<<tg, 256, 0, stream>>>(Pu, Pv, Pw, T);
    }
    hipMemsetAsync(hist, 0, (size_t)3 * 65536 * 4, stream);
    PREFFFT_hist_k<<<NPTS / 256, 256, 0, stream>>>(inputs, hist);
    PREFFFT_scan_k<<<3, 1024, 0, stream>>>(hist);
    PREFFFT_scat_k<<<NPTS / 256, 256, 0, stream>>>(inputs, hist, sortedC);
    {
      dim3 tg(NPTS / 32, 3);
      PREFFFT_samp_k<<<tg, 256, 0, stream>>>(sortedC, T, partial);
    }
    PREFFFT_red_k<<<2048, 256, 0, stream>>>(partial, out);
  } else {
    PREFFFT_fallback_k<<<NPTS / 8, 256, 0, stream>>>(inputs, Pu, Pv, Pw, out);
  }
}